// Round 9
// baseline (267.901 us; speedup 1.0000x reference)
//
#include <hip/hip_runtime.h>
#include <hip/hip_bf16.h>
#include <math.h>

// Problem constants (from reference): D = ATTN = 128, N_NODE = 100000.
#define DIM 128
#define N_NODE_C 100000

typedef __attribute__((ext_vector_type(8))) short  bf16x8;
typedef __attribute__((ext_vector_type(4))) float  f32x4;

__device__ inline unsigned short f2bf_rne(float f) {
    unsigned u = __float_as_uint(f);
    return (unsigned short)((u + 0x7FFFu + ((u >> 16) & 1u)) >> 16);
}
__device__ inline float bf2f(unsigned short u) {
    return __uint_as_float(((unsigned)u) << 16);
}

// ---------------------------------------------------------------------------
// Small projections: qrW[b] = rela_embed[q_rel[b]] @ Wqr_w + Wqr_b   (B rows)
//                    hrW[r] = rela_embed[r]        @ Wr             (RV rows)
// ---------------------------------------------------------------------------
__global__ __launch_bounds__(128) void proj_small(
    const int* __restrict__ q_rel,
    const float* __restrict__ rela,
    const float* __restrict__ Wqr_w,
    const float* __restrict__ Wqr_b,
    const float* __restrict__ Wr,
    float* __restrict__ qrW,
    float* __restrict__ hrW,
    int B)
{
    __shared__ float emb[DIM];
    const int blk = blockIdx.x;
    const int j   = threadIdx.x;

    const float* W;
    float* out;
    float bias = 0.f;
    int row;
    if (blk < B) {
        row  = q_rel[blk];
        W    = Wqr_w;
        out  = qrW + (size_t)blk * DIM;
        bias = Wqr_b[j];
    } else {
        row = blk - B;
        W   = Wr;
        out = hrW + (size_t)(blk - B) * DIM;
    }
    emb[j] = rela[(size_t)row * DIM + j];
    __syncthreads();

    float acc = bias;
#pragma unroll 8
    for (int k = 0; k < DIM; ++k)
        acc += emb[k] * W[k * DIM + j];
    out[j] = acc;
}

// ---------------------------------------------------------------------------
// Pack W[128x128] (f32) into mfma_f32_16x16x32_bf16 B-fragment layout.
// ---------------------------------------------------------------------------
__global__ __launch_bounds__(256) void pack_w(
    const float* __restrict__ W, uint4* __restrict__ Wpack)
{
    const int id   = blockIdx.x * 256 + threadIdx.x;   // 0..2047
    const int ct   = id >> 8;
    const int kb   = (id >> 6) & 3;
    const int lane = id & 63;
    const int col  = ct * 16 + (lane & 15);
    const int k0   = kb * 32 + (lane >> 4) * 8;

    unsigned v[4];
#pragma unroll
    for (int p = 0; p < 4; ++p) {
        unsigned lo = f2bf_rne(W[(size_t)(k0 + 2 * p)     * DIM + col]);
        unsigned hi = f2bf_rne(W[(size_t)(k0 + 2 * p + 1) * DIM + col]);
        v[p] = lo | (hi << 16);
    }
    Wpack[id] = make_uint4(v[0], v[1], v[2], v[3]);
}

// ---------------------------------------------------------------------------
// C[M x 128] = A[M x 128 (f32)] @ W[128 x 128] via bf16 MFMA (fp32 accum).
// Block = 4 waves, wave = 16 rows x 128 cols. Wpack staged in LDS (32 KB).
// C/D layout (HW-verified): col = lane&15, row = (lane>>4)*4 + reg.
// OUTMODE 0: C = f32 [M x 128]        (final GEMM, in-place safe: each wave
//            consumes its own 16 A-rows through registers before storing)
// OUTMODE 1: C = bf16 [M x 128]       (hsW only, tier-B)
// OUTMODE 2: C = bf16 [M x 256] hsub  (cols 0..127 = bf16(A), 128..255 = A@W)
// ---------------------------------------------------------------------------
template <int OUTMODE>
__global__ __launch_bounds__(256) void gemm_mfma(
    const float* A, const uint4* __restrict__ Wpack, void* Cv, int M)
{
    __shared__ uint4 wlds[2048];   // [ct][kb][lane], 32 KB
    const int t = threadIdx.x;
#pragma unroll
    for (int p = 0; p < 8; ++p)
        wlds[p * 256 + t] = Wpack[p * 256 + t];
    __syncthreads();

    const int wave = t >> 6;
    const int lane = t & 63;
    const int r    = lane & 15;
    const int g    = lane >> 4;
    const int row0 = blockIdx.x * 64 + wave * 16;

    int arow = row0 + r;
    if (arow >= M) arow = M - 1;
    const float* Ap = A + (size_t)arow * DIM + g * 8;

    bf16x8 afrag[4];
#pragma unroll
    for (int kb = 0; kb < 4; ++kb) {
        const float4 lo = *(const float4*)(Ap + kb * 32);
        const float4 hi = *(const float4*)(Ap + kb * 32 + 4);
        bf16x8 a;
        a[0] = (short)f2bf_rne(lo.x); a[1] = (short)f2bf_rne(lo.y);
        a[2] = (short)f2bf_rne(lo.z); a[3] = (short)f2bf_rne(lo.w);
        a[4] = (short)f2bf_rne(hi.x); a[5] = (short)f2bf_rne(hi.y);
        a[6] = (short)f2bf_rne(hi.z); a[7] = (short)f2bf_rne(hi.w);
        afrag[kb] = a;
    }

    if (OUTMODE == 2) {
        // Emit bf16(A) row fragments into hsub cols 0..127 (free conversion).
        unsigned short* H = (unsigned short*)Cv;
#pragma unroll
        for (int kb = 0; kb < 4; ++kb)
            *(bf16x8*)&H[(size_t)arow * 256 + kb * 32 + g * 8] = afrag[kb];
    }

    const int cstride = (OUTMODE == 2) ? 256 : DIM;
    const int coff    = (OUTMODE == 2) ? 128 : 0;

#pragma unroll
    for (int ct = 0; ct < 8; ++ct) {
        f32x4 acc = {0.f, 0.f, 0.f, 0.f};
#pragma unroll
        for (int kb = 0; kb < 4; ++kb) {
            bf16x8 b = *(bf16x8*)&wlds[ct * 256 + kb * 64 + lane];
            acc = __builtin_amdgcn_mfma_f32_16x16x32_bf16(afrag[kb], b, acc, 0, 0, 0);
        }
        const int col = ct * 16 + r;
#pragma unroll
        for (int j = 0; j < 4; ++j) {
            const int row = row0 + g * 4 + j;
            if (row < M) {
                if (OUTMODE == 0)
                    ((float*)Cv)[(size_t)row * DIM + col] = acc[j];
                else
                    ((unsigned short*)Cv)[(size_t)row * cstride + coff + col] = f2bf_rne(acc[j]);
            }
        }
    }
}

// ---------------------------------------------------------------------------
// Counting sort by obj: hist -> exclusive scan -> scatter (16 B records).
// ---------------------------------------------------------------------------
__global__ __launch_bounds__(256) void hist_kernel(
    const int* __restrict__ edges, int* __restrict__ deg, int E)
{
    int i = blockIdx.x * 256 + threadIdx.x;
    if (i < E) atomicAdd(&deg[edges[(size_t)i * 6 + 5]], 1);
}

__global__ __launch_bounds__(256) void scan1_kernel(
    const int* __restrict__ in, int* __restrict__ out,
    int* __restrict__ bsum, int n)
{
    __shared__ int ts[256];
    const int tid  = threadIdx.x;
    const int base = blockIdx.x * 2048 + tid * 8;

    int v[8];
    int run = 0;
#pragma unroll
    for (int i = 0; i < 8; ++i) {
        int x = (base + i < n) ? in[base + i] : 0;
        v[i] = run;
        run += x;
    }
    ts[tid] = run;
    __syncthreads();
    for (int off = 1; off < 256; off <<= 1) {
        int x = (tid >= off) ? ts[tid - off] : 0;
        __syncthreads();
        ts[tid] += x;
        __syncthreads();
    }
    const int excl = ts[tid] - run;
#pragma unroll
    for (int i = 0; i < 8; ++i)
        if (base + i < n) out[base + i] = v[i] + excl;
    if (tid == 255) bsum[blockIdx.x] = ts[255];
}

__global__ void scan2_kernel(int* __restrict__ bsum, int nb)
{
    if (blockIdx.x == 0 && threadIdx.x == 0) {
        int run = 0;
        for (int i = 0; i < nb; ++i) { int x = bsum[i]; bsum[i] = run; run += x; }
    }
}

// Adds block offsets; also emits sampled_nodes_idx (merged nodes_kernel).
__global__ __launch_bounds__(256) void scan3_kernel(
    int* __restrict__ offs, int* __restrict__ cursor,
    const int* __restrict__ bsum,
    const int* __restrict__ nodes, float* __restrict__ samp, int n)
{
    int i = blockIdx.x * 256 + threadIdx.x;
    if (i < n) {
        int v = offs[i] + bsum[i >> 11];
        offs[i]   = v;
        cursor[i] = v;
        int nv = nodes[(size_t)i * 2 + 1];
        samp[i] = (nv > -1 && nv < N_NODE_C + 1) ? 1.f : 0.f;
    }
}

// Scatter full edge records {r_idx, rel, sub, e} in obj-sorted order.
__global__ __launch_bounds__(256) void scatter_kernel(
    const int* __restrict__ edges, int* __restrict__ cursor,
    int4* __restrict__ esorted, int E)
{
    int i = blockIdx.x * 256 + threadIdx.x;
    if (i < E) {
        int4 rec;
        rec.x = edges[(size_t)i * 6 + 0];
        rec.y = edges[(size_t)i * 6 + 2];
        rec.z = edges[(size_t)i * 6 + 4];
        rec.w = i;
        int obj = edges[(size_t)i * 6 + 5];
        int pos = atomicAdd(&cursor[obj], 1);
        esorted[pos] = rec;
    }
}

// ---------------------------------------------------------------------------
// Pull-style aggregation, 4 edges per wave concurrently.
// MODE 0 (tier A): combined hsub [N][256] bf16 (hidden | hsW) — 512 B/row gather.
// MODE 1 (tier B): hsWb [N][128] bf16 + hidden f32.
// One int4 record per edge (no edges[] indirection); 512 B row store per node.
// ---------------------------------------------------------------------------
template <int MODE>
__global__ __launch_bounds__(256) void node_agg_kernel(
    const int4* __restrict__ esorted,
    const float* __restrict__ hidden,          // MODE 1 only
    const float* __restrict__ rela,
    const unsigned short* __restrict__ hsub,   // A: N x 256, B: N x 128
    const float* __restrict__ qrW,
    const float* __restrict__ hrW,
    const float* __restrict__ walpha_w,
    const float* __restrict__ walpha_b,
    const int* __restrict__ deg,
    const int* __restrict__ offs,
    float* __restrict__ agg,
    float* __restrict__ alpha_out,
    int N)
{
    const int widx = threadIdx.x >> 6;
    const int lane = threadIdx.x & 63;
    const int o    = blockIdx.x * 4 + widx;
    if (o >= N) return;

    const int q   = lane >> 4;          // quarter 0..3 (one edge each)
    const int l16 = lane & 15;
    const int j   = l16 * 8;            // 8 columns per lane

    const int d = deg[o];
    const int s = offs[o];

    const float4 wwA = *(const float4*)&walpha_w[j];
    const float4 wwB = *(const float4*)&walpha_w[j + 4];
    const float  wb  = walpha_b[0];

    float4 accA = make_float4(0.f, 0.f, 0.f, 0.f);
    float4 accB = make_float4(0.f, 0.f, 0.f, 0.f);

    for (int k = 0; k < d; k += 4) {
        const int kk = k + q;
        if (kk < d) {                   // uniform within the 16-lane quarter
            const int4 rec  = esorted[s + kk];
            const int r_idx = rec.x;
            const int rel   = rec.y;
            const int sub   = rec.z;

            float h0,h1,h2,h3,h4,h5,h6,h7;   // hidden[sub] values
            float w0,w1,w2,w3,w4,w5,w6,w7;   // hsW[sub] values
            if (MODE == 0) {
                const bf16x8 hb = *(const bf16x8*)&hsub[(size_t)sub * 256 + j];
                const bf16x8 pb = *(const bf16x8*)&hsub[(size_t)sub * 256 + 128 + j];
                h0 = bf2f((unsigned short)hb[0]); h1 = bf2f((unsigned short)hb[1]);
                h2 = bf2f((unsigned short)hb[2]); h3 = bf2f((unsigned short)hb[3]);
                h4 = bf2f((unsigned short)hb[4]); h5 = bf2f((unsigned short)hb[5]);
                h6 = bf2f((unsigned short)hb[6]); h7 = bf2f((unsigned short)hb[7]);
                w0 = bf2f((unsigned short)pb[0]); w1 = bf2f((unsigned short)pb[1]);
                w2 = bf2f((unsigned short)pb[2]); w3 = bf2f((unsigned short)pb[3]);
                w4 = bf2f((unsigned short)pb[4]); w5 = bf2f((unsigned short)pb[5]);
                w6 = bf2f((unsigned short)pb[6]); w7 = bf2f((unsigned short)pb[7]);
            } else {
                const float4 hvA = *(const float4*)&hidden[(size_t)sub * DIM + j];
                const float4 hvB = *(const float4*)&hidden[(size_t)sub * DIM + j + 4];
                const bf16x8 pb  = *(const bf16x8*)&hsub[(size_t)sub * DIM + j];
                h0 = hvA.x; h1 = hvA.y; h2 = hvA.z; h3 = hvA.w;
                h4 = hvB.x; h5 = hvB.y; h6 = hvB.z; h7 = hvB.w;
                w0 = bf2f((unsigned short)pb[0]); w1 = bf2f((unsigned short)pb[1]);
                w2 = bf2f((unsigned short)pb[2]); w3 = bf2f((unsigned short)pb[3]);
                w4 = bf2f((unsigned short)pb[4]); w5 = bf2f((unsigned short)pb[5]);
                w6 = bf2f((unsigned short)pb[6]); w7 = bf2f((unsigned short)pb[7]);
            }

            const float4 rvA = *(const float4*)&rela[(size_t)rel * DIM + j];
            const float4 rvB = *(const float4*)&rela[(size_t)rel * DIM + j + 4];
            const float4 bA  = *(const float4*)&hrW[(size_t)rel * DIM + j];
            const float4 bB  = *(const float4*)&hrW[(size_t)rel * DIM + j + 4];
            const float4 cA  = *(const float4*)&qrW[(size_t)r_idx * DIM + j];
            const float4 cB  = *(const float4*)&qrW[(size_t)r_idx * DIM + j + 4];

            float sdot =
                fmaxf(w0 + bA.x + cA.x, 0.f) * wwA.x +
                fmaxf(w1 + bA.y + cA.y, 0.f) * wwA.y +
                fmaxf(w2 + bA.z + cA.z, 0.f) * wwA.z +
                fmaxf(w3 + bA.w + cA.w, 0.f) * wwA.w +
                fmaxf(w4 + bB.x + cB.x, 0.f) * wwB.x +
                fmaxf(w5 + bB.y + cB.y, 0.f) * wwB.y +
                fmaxf(w6 + bB.z + cB.z, 0.f) * wwB.z +
                fmaxf(w7 + bB.w + cB.w, 0.f) * wwB.w;

            // Reduce across the 16-lane quarter.
#pragma unroll
            for (int off = 8; off >= 1; off >>= 1)
                sdot += __shfl_xor(sdot, off, 16);

            const float alpha = 1.f / (1.f + expf(-(sdot + wb)));

            accA.x += alpha * (h0 + rvA.x);
            accA.y += alpha * (h1 + rvA.y);
            accA.z += alpha * (h2 + rvA.z);
            accA.w += alpha * (h3 + rvA.w);
            accB.x += alpha * (h4 + rvB.x);
            accB.y += alpha * (h5 + rvB.y);
            accB.z += alpha * (h6 + rvB.z);
            accB.w += alpha * (h7 + rvB.w);

            if (l16 == 0) alpha_out[rec.w] = alpha;
        }
    }

    // Combine the 4 quarters (same columns live at lane ^16, ^32).
#pragma unroll
    for (int off = 16; off <= 32; off <<= 1) {
        accA.x += __shfl_xor(accA.x, off, 64);
        accA.y += __shfl_xor(accA.y, off, 64);
        accA.z += __shfl_xor(accA.z, off, 64);
        accA.w += __shfl_xor(accA.w, off, 64);
        accB.x += __shfl_xor(accB.x, off, 64);
        accB.y += __shfl_xor(accB.y, off, 64);
        accB.z += __shfl_xor(accB.z, off, 64);
        accB.w += __shfl_xor(accB.w, off, 64);
    }

    if (q == 0) {
        *(float4*)&agg[(size_t)o * DIM + j]     = accA;
        *(float4*)&agg[(size_t)o * DIM + j + 4] = accB;
    }
}

// ---------------------------------------------------------------------------
// Tier-C fallback: push-style edge kernel (inline hs @ Ws), f32 atomics.
// ---------------------------------------------------------------------------
__global__ __launch_bounds__(256) void edge_kernel_fb(
    const int* __restrict__ edges,
    const float* __restrict__ hidden,
    const float* __restrict__ rela,
    const float* __restrict__ Ws,
    const float* __restrict__ qrW,
    const float* __restrict__ hrW,
    const float* __restrict__ walpha_w,
    const float* __restrict__ walpha_b,
    float* __restrict__ agg,
    float* __restrict__ alpha_out,
    int E)
{
    const int widx = threadIdx.x >> 6;
    const int lane = threadIdx.x & 63;
    const int e    = blockIdx.x * 4 + widx;
    const bool valid = (e < E);
    const int ec   = valid ? e : 0;

    const int r_idx = edges[(size_t)ec * 6 + 0];
    const int rel   = edges[(size_t)ec * 6 + 2];
    const int sub   = edges[(size_t)ec * 6 + 4];
    const int obj   = edges[(size_t)ec * 6 + 5];

    const int j = lane * 2;

    const float2 hv = *(const float2*)&hidden[(size_t)sub * DIM + j];
    const float2 rv = *(const float2*)&rela[(size_t)rel * DIM + j];

    __shared__ float hrow[4][DIM];
    *(float2*)&hrow[widx][j] = hv;
    __syncthreads();
    float p0 = 0.f, p1 = 0.f;
#pragma unroll 4
    for (int k = 0; k < DIM; ++k) {
        float hk  = hrow[widx][k];
        float2 w2 = *(const float2*)&Ws[k * DIM + j];
        p0 += hk * w2.x;
        p1 += hk * w2.y;
    }

    const float2 b2 = *(const float2*)&hrW[(size_t)rel * DIM + j];
    const float2 c2 = *(const float2*)&qrW[(size_t)r_idx * DIM + j];
    p0 = fmaxf(p0 + b2.x + c2.x, 0.f);
    p1 = fmaxf(p1 + b2.y + c2.y, 0.f);

    const float2 ww = *(const float2*)&walpha_w[j];
    float s = p0 * ww.x + p1 * ww.y;
#pragma unroll
    for (int off = 32; off >= 1; off >>= 1)
        s += __shfl_xor(s, off, 64);

    const float alpha = 1.f / (1.f + expf(-(s + walpha_b[0])));

    if (valid) {
        const float m0 = alpha * (hv.x + rv.x);
        const float m1 = alpha * (hv.y + rv.y);
        atomicAdd(&agg[(size_t)obj * DIM + j], m0);
        atomicAdd(&agg[(size_t)obj * DIM + j + 1], m1);
        if (lane == 0) alpha_out[e] = alpha;
    }
}

__global__ __launch_bounds__(256, 3) void gemm_n128(
    const float* A,
    const float* __restrict__ W,
    float* C,
    int M)
{
    __shared__ __align__(16) float Alds[64][DIM];
    __shared__ __align__(16) float Wlds[32][DIM];

    const int t    = threadIdx.x;
    const int row0 = blockIdx.x * 64;
    const int tx   = t & 31;
    const int ty   = t >> 5;

#pragma unroll
    for (int p = 0; p < 8; ++p) {
        int idx = p * 1024 + t * 4;
        int r   = idx >> 7;
        int c   = idx & 127;
        int gr  = row0 + r;
        if (gr >= M) gr = M - 1;
        *(float4*)&Alds[r][c] = *(const float4*)&A[(size_t)gr * DIM + c];
    }

    float acc[8][4] = {};

    for (int kk = 0; kk < 4; ++kk) {
        __syncthreads();
        {
            const float* Wg = W + (size_t)kk * 32 * DIM;
#pragma unroll
            for (int p = 0; p < 4; ++p) {
                int idx = p * 1024 + t * 4;
                *(float4*)&Wlds[idx >> 7][idx & 127] = *(const float4*)&Wg[idx];
            }
        }
        __syncthreads();

#pragma unroll 2
        for (int k4 = 0; k4 < 32; k4 += 4) {
            const float4 w0 = *(const float4*)&Wlds[k4 + 0][tx * 4];
            const float4 w1 = *(const float4*)&Wlds[k4 + 1][tx * 4];
            const float4 w2 = *(const float4*)&Wlds[k4 + 2][tx * 4];
            const float4 w3 = *(const float4*)&Wlds[k4 + 3][tx * 4];
#pragma unroll
            for (int i = 0; i < 8; ++i) {
                const float4 a = *(const float4*)&Alds[ty * 8 + i][kk * 32 + k4];
                acc[i][0] = fmaf(a.w, w3.x, fmaf(a.z, w2.x, fmaf(a.y, w1.x, fmaf(a.x, w0.x, acc[i][0]))));
                acc[i][1] = fmaf(a.w, w3.y, fmaf(a.z, w2.y, fmaf(a.y, w1.y, fmaf(a.x, w0.y, acc[i][1]))));
                acc[i][2] = fmaf(a.w, w3.z, fmaf(a.z, w2.z, fmaf(a.y, w1.z, fmaf(a.x, w0.z, acc[i][2]))));
                acc[i][3] = fmaf(a.w, w3.w, fmaf(a.z, w2.w, fmaf(a.y, w1.w, fmaf(a.x, w0.w, acc[i][3]))));
            }
        }
    }
    __syncthreads();

#pragma unroll
    for (int i = 0; i < 8; ++i) {
        int gr = row0 + ty * 8 + i;
        if (gr < M) {
            float4 v = make_float4(acc[i][0], acc[i][1], acc[i][2], acc[i][3]);
            *(float4*)&C[(size_t)gr * DIM + tx * 4] = v;
        }
    }
}

__global__ __launch_bounds__(256) void nodes_kernel(
    const int* __restrict__ nodes, float* __restrict__ out, int N)
{
    int i = blockIdx.x * 256 + threadIdx.x;
    if (i < N) {
        int v = nodes[(size_t)i * 2 + 1];
        out[i] = (v > -1 && v < N_NODE_C + 1) ? 1.f : 0.f;
    }
}

// ---------------------------------------------------------------------------
extern "C" void kernel_launch(void* const* d_in, const int* in_sizes, int n_in,
                              void* d_out, int out_size, void* d_ws, size_t ws_size,
                              hipStream_t stream)
{
    const int*   q_rel    = (const int*)d_in[1];
    const float* hidden   = (const float*)d_in[2];
    const int*   edges    = (const int*)d_in[3];
    const int*   nodes    = (const int*)d_in[4];
    const float* rela     = (const float*)d_in[5];
    const float* Ws       = (const float*)d_in[6];
    const float* Wr       = (const float*)d_in[7];
    const float* Wqr_w    = (const float*)d_in[8];
    const float* Wqr_b    = (const float*)d_in[9];
    const float* walpha_w = (const float*)d_in[10];
    const float* walpha_b = (const float*)d_in[11];
    const float* Wh       = (const float*)d_in[12];

    const int B  = in_sizes[1];
    const int N  = in_sizes[2] / DIM;
    const int E  = in_sizes[3] / 6;
    const int RV = in_sizes[5] / DIM;

    float* out       = (float*)d_out;
    float* agg       = out;                          // N*128
    float* alpha_out = out + (size_t)N * DIM;        // E
    float* samp      = alpha_out + (size_t)E;        // N

    // Workspace layout (16-B alignment maintained in declaration order).
    char* p = (char*)d_ws;
    float* qrW = (float*)p;       p += (size_t)B * DIM * sizeof(float);
    float* hrW = (float*)p;       p += (size_t)RV * DIM * sizeof(float);
    uint4* wpack_s = (uint4*)p;   p += 2048 * sizeof(uint4);
    uint4* wpack_h = (uint4*)p;   p += 2048 * sizeof(uint4);
    int4*  esorted = (int4*)p;    p += (size_t)E * sizeof(int4);
    unsigned short* hsub = (unsigned short*)p;   // tier A: N*256, tier B: N*128

    const size_t base_bytes = (size_t)(p - (char*)d_ws);
    const size_t int_bytes  = ((size_t)3 * N + 128) * sizeof(int);
    const size_t need_A = base_bytes + (size_t)N * 256 * sizeof(unsigned short) + int_bytes;
    const size_t need_B = base_bytes + (size_t)N * DIM * sizeof(unsigned short) + int_bytes;

    proj_small<<<B + RV, 128, 0, stream>>>(q_rel, rela, Wqr_w, Wqr_b, Wr, qrW, hrW, B);

    if (ws_size >= need_B) {
        const bool tierA = (ws_size >= need_A);
        const size_t hsub_elems = tierA ? (size_t)N * 256 : (size_t)N * DIM;
        int* deg    = (int*)(hsub + hsub_elems);
        int* offs   = deg + N;
        int* cursor = offs + N;
        int* bsum   = cursor + N;

        pack_w<<<8, 256, 0, stream>>>(Ws, wpack_s);
        pack_w<<<8, 256, 0, stream>>>(Wh, wpack_h);

        if (tierA)
            gemm_mfma<2><<<(N + 63) / 64, 256, 0, stream>>>(hidden, wpack_s, hsub, N);
        else
            gemm_mfma<1><<<(N + 63) / 64, 256, 0, stream>>>(hidden, wpack_s, hsub, N);

        hipMemsetAsync(deg, 0, (size_t)N * sizeof(int), stream);
        hist_kernel<<<(E + 255) / 256, 256, 0, stream>>>(edges, deg, E);

        const int nb = (N + 2047) / 2048;            // <= 128 (bsum capacity)
        scan1_kernel<<<nb, 256, 0, stream>>>(deg, offs, bsum, N);
        scan2_kernel<<<1, 64, 0, stream>>>(bsum, nb);
        scan3_kernel<<<(N + 255) / 256, 256, 0, stream>>>(offs, cursor, bsum, nodes, samp, N);
        scatter_kernel<<<(E + 255) / 256, 256, 0, stream>>>(edges, cursor, esorted, E);

        if (tierA)
            node_agg_kernel<0><<<(N + 3) / 4, 256, 0, stream>>>(
                esorted, hidden, rela, hsub, qrW, hrW, walpha_w, walpha_b,
                deg, offs, agg, alpha_out, N);
        else
            node_agg_kernel<1><<<(N + 3) / 4, 256, 0, stream>>>(
                esorted, hidden, rela, hsub, qrW, hrW, walpha_w, walpha_b,
                deg, offs, agg, alpha_out, N);

        // hidden_new = agg @ Wh, in place over d_out[0 : N*128].
        gemm_mfma<0><<<(N + 63) / 64, 256, 0, stream>>>(agg, wpack_h, out, N);
    } else {
        // --- tier C fallback: push-style with atomics, fp32 GEMM ---
        hipMemsetAsync(agg, 0, (size_t)N * DIM * sizeof(float), stream);
        edge_kernel_fb<<<(E + 3) / 4, 256, 0, stream>>>(
            edges, hidden, rela, Ws, qrW, hrW, walpha_w, walpha_b,
            agg, alpha_out, E);
        gemm_n128<<<(N + 63) / 64, 256, 0, stream>>>(agg, Wh, out, N);
        nodes_kernel<<<(N + 255) / 256, 256, 0, stream>>>(nodes, samp, N);
    }
}

// Round 10
// 228.565 us; speedup vs baseline: 1.1721x; 1.1721x over previous
//
#include <hip/hip_runtime.h>
#include <hip/hip_bf16.h>
#include <math.h>

// Problem constants (from reference): D = ATTN = 128, N_NODE = 100000.
#define DIM 128
#define N_NODE_C 100000

typedef __attribute__((ext_vector_type(8))) short  bf16x8;
typedef __attribute__((ext_vector_type(4))) float  f32x4;

__device__ inline unsigned short f2bf_rne(float f) {
    unsigned u = __float_as_uint(f);
    return (unsigned short)((u + 0x7FFFu + ((u >> 16) & 1u)) >> 16);
}
__device__ inline float bf2f(unsigned short u) {
    return __uint_as_float(((unsigned)u) << 16);
}

// ---------------------------------------------------------------------------
// Fused setup kernel (128 threads/block):
//   blocks [0, B)          : qrW[b]   = rela[q_rel[b]] @ Wqr_w + Wqr_b
//   blocks [B, B+RV)       : relhr[r] = [ rela[r] @ Wr | rela[r] ]   (256 cols)
//   blocks [B+RV, B+RV+32) : pack Ws (16 blocks) then Wh (16 blocks) into
//                            mfma_f32_16x16x32_bf16 B-fragment layout.
// ---------------------------------------------------------------------------
__global__ __launch_bounds__(128) void setup_kernel(
    const int* __restrict__ q_rel,
    const float* __restrict__ rela,
    const float* __restrict__ Wqr_w,
    const float* __restrict__ Wqr_b,
    const float* __restrict__ Wr,
    const float* __restrict__ Ws,
    const float* __restrict__ Wh,
    float* __restrict__ qrW,
    float* __restrict__ relhr,
    uint4* __restrict__ wpack_s,
    uint4* __restrict__ wpack_h,
    int B, int RV)
{
    const int blk = blockIdx.x;
    const int j   = threadIdx.x;

    if (blk < B + RV) {
        __shared__ float emb[DIM];
        const float* W;
        float* out;
        float bias = 0.f;
        int row;
        if (blk < B) {
            row  = q_rel[blk];
            W    = Wqr_w;
            out  = qrW + (size_t)blk * DIM;
            bias = Wqr_b[j];
        } else {
            row = blk - B;
            W   = Wr;
            out = relhr + (size_t)(blk - B) * 256;
        }
        emb[j] = rela[(size_t)row * DIM + j];
        __syncthreads();

        float acc = bias;
#pragma unroll 8
        for (int k = 0; k < DIM; ++k)
            acc += emb[k] * W[k * DIM + j];
        out[j] = acc;
        if (blk >= B)
            out[128 + j] = emb[j];      // rela copy: free (already in LDS)
        return;
    }

    // --- pack path ---
    const int pid = blk - (B + RV);          // 0..31
    const float* W = (pid < 16) ? Ws : Wh;
    uint4* dst     = (pid < 16) ? wpack_s : wpack_h;
    const int id   = (pid & 15) * 128 + j;   // 0..2047
    const int ct   = id >> 8;
    const int kb   = (id >> 6) & 3;
    const int lane = id & 63;
    const int col  = ct * 16 + (lane & 15);
    const int k0   = kb * 32 + (lane >> 4) * 8;

    unsigned v[4];
#pragma unroll
    for (int p = 0; p < 4; ++p) {
        unsigned lo = f2bf_rne(W[(size_t)(k0 + 2 * p)     * DIM + col]);
        unsigned hi = f2bf_rne(W[(size_t)(k0 + 2 * p + 1) * DIM + col]);
        v[p] = lo | (hi << 16);
    }
    dst[id] = make_uint4(v[0], v[1], v[2], v[3]);
}

// ---------------------------------------------------------------------------
// Fused GEMM (OUTMODE 2) + histogram. Heterogeneous grid:
//   blocks [0, Nb)      : hsub[M x 256] bf16 = [ bf16(A) | A @ W ]
//   blocks [Nb, Nb+Hb)  : deg histogram of edges obj column.
// C/D layout (HW-verified): col = lane&15, row = (lane>>4)*4 + reg.
// ---------------------------------------------------------------------------
__global__ __launch_bounds__(256) void gemm_hist_kernel(
    const float* __restrict__ A, const uint4* __restrict__ Wpack,
    unsigned short* __restrict__ H, int M,
    const int* __restrict__ edges, int* __restrict__ deg, int E, int Nb)
{
    if ((int)blockIdx.x >= Nb) {
        int i = ((int)blockIdx.x - Nb) * 256 + threadIdx.x;
        if (i < E) atomicAdd(&deg[edges[(size_t)i * 6 + 5]], 1);
        return;
    }

    __shared__ uint4 wlds[2048];   // [ct][kb][lane], 32 KB
    const int t = threadIdx.x;
#pragma unroll
    for (int p = 0; p < 8; ++p)
        wlds[p * 256 + t] = Wpack[p * 256 + t];
    __syncthreads();

    const int wave = t >> 6;
    const int lane = t & 63;
    const int r    = lane & 15;
    const int g    = lane >> 4;
    const int row0 = blockIdx.x * 64 + wave * 16;

    int arow = row0 + r;
    if (arow >= M) arow = M - 1;
    const float* Ap = A + (size_t)arow * DIM + g * 8;

    bf16x8 afrag[4];
#pragma unroll
    for (int kb = 0; kb < 4; ++kb) {
        const float4 lo = *(const float4*)(Ap + kb * 32);
        const float4 hi = *(const float4*)(Ap + kb * 32 + 4);
        bf16x8 a;
        a[0] = (short)f2bf_rne(lo.x); a[1] = (short)f2bf_rne(lo.y);
        a[2] = (short)f2bf_rne(lo.z); a[3] = (short)f2bf_rne(lo.w);
        a[4] = (short)f2bf_rne(hi.x); a[5] = (short)f2bf_rne(hi.y);
        a[6] = (short)f2bf_rne(hi.z); a[7] = (short)f2bf_rne(hi.w);
        afrag[kb] = a;
    }

    // bf16(A) into cols 0..127 (free conversion).
#pragma unroll
    for (int kb = 0; kb < 4; ++kb)
        *(bf16x8*)&H[(size_t)arow * 256 + kb * 32 + g * 8] = afrag[kb];

#pragma unroll
    for (int ct = 0; ct < 8; ++ct) {
        f32x4 acc = {0.f, 0.f, 0.f, 0.f};
#pragma unroll
        for (int kb = 0; kb < 4; ++kb) {
            bf16x8 b = *(bf16x8*)&wlds[ct * 256 + kb * 64 + lane];
            acc = __builtin_amdgcn_mfma_f32_16x16x32_bf16(afrag[kb], b, acc, 0, 0, 0);
        }
        const int col = ct * 16 + r;
#pragma unroll
        for (int jj = 0; jj < 4; ++jj) {
            const int row = row0 + g * 4 + jj;
            if (row < M)
                H[(size_t)row * 256 + 128 + col] = f2bf_rne(acc[jj]);
        }
    }
}

// ---------------------------------------------------------------------------
// Plain MFMA GEMM, f32 out (final agg @ Wh). In-place safe: each wave
// consumes its own 16 A-rows through registers before storing them.
// ---------------------------------------------------------------------------
__global__ __launch_bounds__(256) void gemm_mfma_f32(
    const float* A, const uint4* __restrict__ Wpack, float* C, int M)
{
    __shared__ uint4 wlds[2048];
    const int t = threadIdx.x;
#pragma unroll
    for (int p = 0; p < 8; ++p)
        wlds[p * 256 + t] = Wpack[p * 256 + t];
    __syncthreads();

    const int wave = t >> 6;
    const int lane = t & 63;
    const int r    = lane & 15;
    const int g    = lane >> 4;
    const int row0 = blockIdx.x * 64 + wave * 16;

    int arow = row0 + r;
    if (arow >= M) arow = M - 1;
    const float* Ap = A + (size_t)arow * DIM + g * 8;

    bf16x8 afrag[4];
#pragma unroll
    for (int kb = 0; kb < 4; ++kb) {
        const float4 lo = *(const float4*)(Ap + kb * 32);
        const float4 hi = *(const float4*)(Ap + kb * 32 + 4);
        bf16x8 a;
        a[0] = (short)f2bf_rne(lo.x); a[1] = (short)f2bf_rne(lo.y);
        a[2] = (short)f2bf_rne(lo.z); a[3] = (short)f2bf_rne(lo.w);
        a[4] = (short)f2bf_rne(hi.x); a[5] = (short)f2bf_rne(hi.y);
        a[6] = (short)f2bf_rne(hi.z); a[7] = (short)f2bf_rne(hi.w);
        afrag[kb] = a;
    }

#pragma unroll
    for (int ct = 0; ct < 8; ++ct) {
        f32x4 acc = {0.f, 0.f, 0.f, 0.f};
#pragma unroll
        for (int kb = 0; kb < 4; ++kb) {
            bf16x8 b = *(bf16x8*)&wlds[ct * 256 + kb * 64 + lane];
            acc = __builtin_amdgcn_mfma_f32_16x16x32_bf16(afrag[kb], b, acc, 0, 0, 0);
        }
        const int col = ct * 16 + r;
#pragma unroll
        for (int jj = 0; jj < 4; ++jj) {
            const int row = row0 + g * 4 + jj;
            if (row < M)
                C[(size_t)row * DIM + col] = acc[jj];
        }
    }
}

// ---------------------------------------------------------------------------
// Sort scaffolding.
// ---------------------------------------------------------------------------
__global__ __launch_bounds__(256) void scan1_kernel(
    const int* __restrict__ in, int* __restrict__ out,
    int* __restrict__ bsum, int n)
{
    __shared__ int ts[256];
    const int tid  = threadIdx.x;
    const int base = blockIdx.x * 2048 + tid * 8;

    int v[8];
    int run = 0;
#pragma unroll
    for (int i = 0; i < 8; ++i) {
        int x = (base + i < n) ? in[base + i] : 0;
        v[i] = run;
        run += x;
    }
    ts[tid] = run;
    __syncthreads();
    for (int off = 1; off < 256; off <<= 1) {
        int x = (tid >= off) ? ts[tid - off] : 0;
        __syncthreads();
        ts[tid] += x;
        __syncthreads();
    }
    const int excl = ts[tid] - run;
#pragma unroll
    for (int i = 0; i < 8; ++i)
        if (base + i < n) out[base + i] = v[i] + excl;
    if (tid == 255) bsum[blockIdx.x] = ts[255];
}

// Adds cross-block prefix (computed in-block; bsum holds block TOTALS),
// duplicates into cursor, and emits sampled_nodes_idx.
__global__ __launch_bounds__(256) void scan3_kernel(
    int* __restrict__ offs, int* __restrict__ cursor,
    const int* __restrict__ bsum,
    const int* __restrict__ nodes, float* __restrict__ samp, int n)
{
    __shared__ int pref;
    if (threadIdx.x == 0) {
        int run = 0;
        const int lim = blockIdx.x >> 3;   // 8 scan3 blocks per scan1 block
        for (int i = 0; i < lim; ++i) run += bsum[i];
        pref = run;
    }
    __syncthreads();
    int i = blockIdx.x * 256 + threadIdx.x;
    if (i < n) {
        int v = offs[i] + pref;
        offs[i]   = v;
        cursor[i] = v;
        int nv = nodes[(size_t)i * 2 + 1];
        samp[i] = (nv > -1 && nv < N_NODE_C + 1) ? 1.f : 0.f;
    }
}

// Scatter full edge records {r_idx, rel, sub, e} in obj-sorted order.
__global__ __launch_bounds__(256) void scatter_kernel(
    const int* __restrict__ edges, int* __restrict__ cursor,
    int4* __restrict__ esorted, int E)
{
    int i = blockIdx.x * 256 + threadIdx.x;
    if (i < E) {
        int4 rec;
        rec.x = edges[(size_t)i * 6 + 0];
        rec.y = edges[(size_t)i * 6 + 2];
        rec.z = edges[(size_t)i * 6 + 4];
        rec.w = i;
        int obj = edges[(size_t)i * 6 + 5];
        int pos = atomicAdd(&cursor[obj], 1);
        esorted[pos] = rec;
    }
}

// ---------------------------------------------------------------------------
// Pull aggregation: ONE NODE PER 16-LANE GROUP (4 nodes per wave).
// Group serially walks its node's edges (2-deep record prefetch); 8 cols/lane.
// No cross-quarter combine; one 512 B row store per node; fast sigmoid.
// ---------------------------------------------------------------------------
__global__ __launch_bounds__(256) void node_agg_kernel(
    const int4* __restrict__ esorted,
    const unsigned short* __restrict__ hsub,   // N x 256 bf16: [hidden | hsW]
    const float* __restrict__ relhr,           // RV x 256 f32: [hrW | rela]
    const float* __restrict__ qrW,             // B x 128 f32
    const float* __restrict__ walpha_w,
    const float* __restrict__ walpha_b,
    const int* __restrict__ deg,
    const int* __restrict__ offs,
    float* __restrict__ agg,
    float* __restrict__ alpha_out,
    int N)
{
    const int o = (blockIdx.x * 256 + threadIdx.x) >> 4;   // node = group id
    if (o >= N) return;
    const int l16 = threadIdx.x & 15;
    const int j   = l16 * 8;

    const int d = deg[o];
    const int s = offs[o];

    const float4 wwA = *(const float4*)&walpha_w[j];
    const float4 wwB = *(const float4*)&walpha_w[j + 4];
    const float  wb  = walpha_b[0];

    float4 accA = make_float4(0.f, 0.f, 0.f, 0.f);
    float4 accB = make_float4(0.f, 0.f, 0.f, 0.f);

    int4 rec = (d > 0) ? esorted[s] : make_int4(0, 0, 0, 0);
    for (int k = 0; k < d; ++k) {
        const int4 nrec = (k + 1 < d) ? esorted[s + k + 1] : rec;  // prefetch

        const int r_idx = rec.x;
        const int rel   = rec.y;
        const int sub   = rec.z;

        const bf16x8 hb = *(const bf16x8*)&hsub[(size_t)sub * 256 + j];
        const bf16x8 pb = *(const bf16x8*)&hsub[(size_t)sub * 256 + 128 + j];
        const float* rr = &relhr[(size_t)rel * 256];
        const float4 bA  = *(const float4*)&rr[j];
        const float4 bB  = *(const float4*)&rr[j + 4];
        const float4 rvA = *(const float4*)&rr[128 + j];
        const float4 rvB = *(const float4*)&rr[128 + j + 4];
        const float4 cA  = *(const float4*)&qrW[(size_t)r_idx * DIM + j];
        const float4 cB  = *(const float4*)&qrW[(size_t)r_idx * DIM + j + 4];

        float sdot =
            fmaxf(bf2f((unsigned short)pb[0]) + bA.x + cA.x, 0.f) * wwA.x +
            fmaxf(bf2f((unsigned short)pb[1]) + bA.y + cA.y, 0.f) * wwA.y +
            fmaxf(bf2f((unsigned short)pb[2]) + bA.z + cA.z, 0.f) * wwA.z +
            fmaxf(bf2f((unsigned short)pb[3]) + bA.w + cA.w, 0.f) * wwA.w +
            fmaxf(bf2f((unsigned short)pb[4]) + bB.x + cB.x, 0.f) * wwB.x +
            fmaxf(bf2f((unsigned short)pb[5]) + bB.y + cB.y, 0.f) * wwB.y +
            fmaxf(bf2f((unsigned short)pb[6]) + bB.z + cB.z, 0.f) * wwB.z +
            fmaxf(bf2f((unsigned short)pb[7]) + bB.w + cB.w, 0.f) * wwB.w;

#pragma unroll
        for (int off = 8; off >= 1; off >>= 1)
            sdot += __shfl_xor(sdot, off, 16);

        // alpha = sigmoid(sdot + wb), fast path: v_exp_f32 + v_rcp_f32.
        const float alpha =
            __builtin_amdgcn_rcpf(1.f + __expf(-(sdot + wb)));

        accA.x += alpha * (bf2f((unsigned short)hb[0]) + rvA.x);
        accA.y += alpha * (bf2f((unsigned short)hb[1]) + rvA.y);
        accA.z += alpha * (bf2f((unsigned short)hb[2]) + rvA.z);
        accA.w += alpha * (bf2f((unsigned short)hb[3]) + rvA.w);
        accB.x += alpha * (bf2f((unsigned short)hb[4]) + rvB.x);
        accB.y += alpha * (bf2f((unsigned short)hb[5]) + rvB.y);
        accB.z += alpha * (bf2f((unsigned short)hb[6]) + rvB.z);
        accB.w += alpha * (bf2f((unsigned short)hb[7]) + rvB.w);

        if (l16 == 0) alpha_out[rec.w] = alpha;
        rec = nrec;
    }

    *(float4*)&agg[(size_t)o * DIM + j]     = accA;
    *(float4*)&agg[(size_t)o * DIM + j + 4] = accB;
}

// ---------------------------------------------------------------------------
// Tier-C fallback: push-style edge kernel (inline hs @ Ws), f32 atomics.
// ---------------------------------------------------------------------------
__global__ __launch_bounds__(256) void edge_kernel_fb(
    const int* __restrict__ edges,
    const float* __restrict__ hidden,
    const float* __restrict__ rela,
    const float* __restrict__ Ws,
    const float* __restrict__ qrW,
    const float* __restrict__ relhr,
    const float* __restrict__ walpha_w,
    const float* __restrict__ walpha_b,
    float* __restrict__ agg,
    float* __restrict__ alpha_out,
    int E)
{
    const int widx = threadIdx.x >> 6;
    const int lane = threadIdx.x & 63;
    const int e    = blockIdx.x * 4 + widx;
    const bool valid = (e < E);
    const int ec   = valid ? e : 0;

    const int r_idx = edges[(size_t)ec * 6 + 0];
    const int rel   = edges[(size_t)ec * 6 + 2];
    const int sub   = edges[(size_t)ec * 6 + 4];
    const int obj   = edges[(size_t)ec * 6 + 5];

    const int j = lane * 2;

    const float2 hv = *(const float2*)&hidden[(size_t)sub * DIM + j];
    const float2 rv = *(const float2*)&rela[(size_t)rel * DIM + j];

    __shared__ float hrow[4][DIM];
    *(float2*)&hrow[widx][j] = hv;
    __syncthreads();
    float p0 = 0.f, p1 = 0.f;
#pragma unroll 4
    for (int k = 0; k < DIM; ++k) {
        float hk  = hrow[widx][k];
        float2 w2 = *(const float2*)&Ws[k * DIM + j];
        p0 += hk * w2.x;
        p1 += hk * w2.y;
    }

    const float2 b2 = *(const float2*)&relhr[(size_t)rel * 256 + j];
    const float2 c2 = *(const float2*)&qrW[(size_t)r_idx * DIM + j];
    p0 = fmaxf(p0 + b2.x + c2.x, 0.f);
    p1 = fmaxf(p1 + b2.y + c2.y, 0.f);

    const float2 ww = *(const float2*)&walpha_w[j];
    float s = p0 * ww.x + p1 * ww.y;
#pragma unroll
    for (int off = 32; off >= 1; off >>= 1)
        s += __shfl_xor(s, off, 64);

    const float alpha = 1.f / (1.f + expf(-(s + walpha_b[0])));

    if (valid) {
        const float m0 = alpha * (hv.x + rv.x);
        const float m1 = alpha * (hv.y + rv.y);
        atomicAdd(&agg[(size_t)obj * DIM + j], m0);
        atomicAdd(&agg[(size_t)obj * DIM + j + 1], m1);
        if (lane == 0) alpha_out[e] = alpha;
    }
}

__global__ __launch_bounds__(256, 3) void gemm_n128(
    const float* A,
    const float* __restrict__ W,
    float* C,
    int M)
{
    __shared__ __align__(16) float Alds[64][DIM];
    __shared__ __align__(16) float Wlds[32][DIM];

    const int t    = threadIdx.x;
    const int row0 = blockIdx.x * 64;
    const int tx   = t & 31;
    const int ty   = t >> 5;

#pragma unroll
    for (int p = 0; p < 8; ++p) {
        int idx = p * 1024 + t * 4;
        int r   = idx >> 7;
        int c   = idx & 127;
        int gr  = row0 + r;
        if (gr >= M) gr = M - 1;
        *(float4*)&Alds[r][c] = *(const float4*)&A[(size_t)gr * DIM + c];
    }

    float acc[8][4] = {};

    for (int kk = 0; kk < 4; ++kk) {
        __syncthreads();
        {
            const float* Wg = W + (size_t)kk * 32 * DIM;
#pragma unroll
            for (int p = 0; p < 4; ++p) {
                int idx = p * 1024 + t * 4;
                *(float4*)&Wlds[idx >> 7][idx & 127] = *(const float4*)&Wg[idx];
            }
        }
        __syncthreads();

#pragma unroll 2
        for (int k4 = 0; k4 < 32; k4 += 4) {
            const float4 w0 = *(const float4*)&Wlds[k4 + 0][tx * 4];
            const float4 w1 = *(const float4*)&Wlds[k4 + 1][tx * 4];
            const float4 w2 = *(const float4*)&Wlds[k4 + 2][tx * 4];
            const float4 w3 = *(const float4*)&Wlds[k4 + 3][tx * 4];
#pragma unroll
            for (int i = 0; i < 8; ++i) {
                const float4 a = *(const float4*)&Alds[ty * 8 + i][kk * 32 + k4];
                acc[i][0] = fmaf(a.w, w3.x, fmaf(a.z, w2.x, fmaf(a.y, w1.x, fmaf(a.x, w0.x, acc[i][0]))));
                acc[i][1] = fmaf(a.w, w3.y, fmaf(a.z, w2.y, fmaf(a.y, w1.y, fmaf(a.x, w0.y, acc[i][1]))));
                acc[i][2] = fmaf(a.w, w3.z, fmaf(a.z, w2.z, fmaf(a.y, w1.z, fmaf(a.x, w0.z, acc[i][2]))));
                acc[i][3] = fmaf(a.w, w3.w, fmaf(a.z, w2.w, fmaf(a.y, w1.w, fmaf(a.x, w0.w, acc[i][3]))));
            }
        }
    }
    __syncthreads();

#pragma unroll
    for (int i = 0; i < 8; ++i) {
        int gr = row0 + ty * 8 + i;
        if (gr < M) {
            float4 v = make_float4(acc[i][0], acc[i][1], acc[i][2], acc[i][3]);
            *(float4*)&C[(size_t)gr * DIM + tx * 4] = v;
        }
    }
}

__global__ __launch_bounds__(256) void nodes_kernel(
    const int* __restrict__ nodes, float* __restrict__ out, int N)
{
    int i = blockIdx.x * 256 + threadIdx.x;
    if (i < N) {
        int v = nodes[(size_t)i * 2 + 1];
        out[i] = (v > -1 && v < N_NODE_C + 1) ? 1.f : 0.f;
    }
}

// ---------------------------------------------------------------------------
extern "C" void kernel_launch(void* const* d_in, const int* in_sizes, int n_in,
                              void* d_out, int out_size, void* d_ws, size_t ws_size,
                              hipStream_t stream)
{
    const int*   q_rel    = (const int*)d_in[1];
    const float* hidden   = (const float*)d_in[2];
    const int*   edges    = (const int*)d_in[3];
    const int*   nodes    = (const int*)d_in[4];
    const float* rela     = (const float*)d_in[5];
    const float* Ws       = (const float*)d_in[6];
    const float* Wr       = (const float*)d_in[7];
    const float* Wqr_w    = (const float*)d_in[8];
    const float* Wqr_b    = (const float*)d_in[9];
    const float* walpha_w = (const float*)d_in[10];
    const float* walpha_b = (const float*)d_in[11];
    const float* Wh       = (const float*)d_in[12];

    const int B  = in_sizes[1];
    const int N  = in_sizes[2] / DIM;
    const int E  = in_sizes[3] / 6;
    const int RV = in_sizes[5] / DIM;

    float* out       = (float*)d_out;
    float* agg       = out;                          // N*128
    float* alpha_out = out + (size_t)N * DIM;        // E
    float* samp      = alpha_out + (size_t)E;        // N

    // Workspace layout (16-B alignment maintained in declaration order).
    char* p = (char*)d_ws;
    float* qrW   = (float*)p;     p += (size_t)B * DIM * sizeof(float);
    float* relhr = (float*)p;     p += (size_t)RV * 256 * sizeof(float);
    uint4* wpack_s = (uint4*)p;   p += 2048 * sizeof(uint4);
    uint4* wpack_h = (uint4*)p;   p += 2048 * sizeof(uint4);
    int4*  esorted = (int4*)p;    p += (size_t)E * sizeof(int4);
    unsigned short* hsub = (unsigned short*)p;
    const size_t base_bytes = (size_t)(p - (char*)d_ws);

    const size_t need_A = base_bytes
        + (size_t)N * 256 * sizeof(unsigned short)
        + ((size_t)3 * N + 128) * sizeof(int);

    setup_kernel<<<B + RV + 32, 128, 0, stream>>>(
        q_rel, rela, Wqr_w, Wqr_b, Wr, Ws, Wh,
        qrW, relhr, wpack_s, wpack_h, B, RV);

    if (ws_size >= need_A) {
        int* deg    = (int*)(hsub + (size_t)N * 256);
        int* offs   = deg + N;
        int* cursor = offs + N;
        int* bsum   = cursor + N;

        hipMemsetAsync(deg, 0, (size_t)N * sizeof(int), stream);

        const int Nb = (N + 63) / 64;
        const int Hb = (E + 255) / 256;
        gemm_hist_kernel<<<Nb + Hb, 256, 0, stream>>>(
            hidden, wpack_s, hsub, N, edges, deg, E, Nb);

        const int nb = (N + 2047) / 2048;            // <= 128 (bsum capacity)
        scan1_kernel<<<nb, 256, 0, stream>>>(deg, offs, bsum, N);
        scan3_kernel<<<(N + 255) / 256, 256, 0, stream>>>(
            offs, cursor, bsum, nodes, samp, N);
        scatter_kernel<<<(E + 255) / 256, 256, 0, stream>>>(
            edges, cursor, esorted, E);

        node_agg_kernel<<<(N * 16 + 255) / 256, 256, 0, stream>>>(
            esorted, hsub, relhr, qrW, walpha_w, walpha_b,
            deg, offs, agg, alpha_out, N);

        // hidden_new = agg @ Wh, in place over d_out[0 : N*128].
        gemm_mfma_f32<<<(N + 63) / 64, 256, 0, stream>>>(agg, wpack_h, out, N);
    } else {
        // --- tier C fallback: push-style with atomics, fp32 GEMM ---
        hipMemsetAsync(agg, 0, (size_t)N * DIM * sizeof(float), stream);
        edge_kernel_fb<<<(E + 3) / 4, 256, 0, stream>>>(
            edges, hidden, rela, Ws, qrW, relhr, walpha_w, walpha_b,
            agg, alpha_out, E);
        gemm_n128<<<(N + 63) / 64, 256, 0, stream>>>(agg, Wh, out, N);
        nodes_kernel<<<(N + 255) / 256, 256, 0, stream>>>(nodes, samp, N);
    }
}